// Round 14
// baseline (142.556 us; speedup 1.0000x reference)
//
#include <hip/hip_runtime.h>
#include <cstdint>
#include <cstddef>

// FiBiNET fused inference — single fused MFMA kernel + weight repack.
// R21b: non-temporal weight loads (compile fix: __builtin_nontemporal_load
// requires a clang ext-vector pointer, not HIP_vector_type int4 — use
// i32x4 ext_vector_type). Theory unchanged: R20 cut VALUBusy 42->36% with
// zero time delta -> VALU-issue exonerated (4th pipe). Remaining anomaly:
// pair-slot time invariant to wave count (R15 2w = R16 3w) => a shared
// per-CU resource saturates. Unprobed candidate: L1 miss path. Weights have
// ZERO L1 reuse (each pair read once per CU; 1.72MB stream vs 32KB L1) yet
// every load allocates+serializes through L1 MSHRs; sustaining ~46 GB/s/CU
// at ~200cy L2 latency needs ~60 in-flight misses ~= typical MSHR budget.
// Fix: nontemporal (nt) on the 5 weight loads/pair -> L1 bypass. Caching
// hint only — bit-identical numerics. Base = R15 verbatim (best verified
// k_main 43.4us; scalar glue, setprio, K=32 t-path, pure-DS pair advance).

#define F_FIELDS 26
#define P_PAIRS 325
#define PAD_PAIRS 336
#define BATCH 16384
#define BN_EPS 1e-3f
#define ROWS 64   // batch rows per block = 4 m-tiles per wave

typedef short bf16x8 __attribute__((ext_vector_type(8)));
typedef float f32x4 __attribute__((ext_vector_type(4)));
typedef int   i32x4 __attribute__((ext_vector_type(4)));

struct PairTab { unsigned char iu[PAD_PAIRS]; unsigned char ju[PAD_PAIRS]; };
static constexpr PairTab make_pairs() {
    PairTab t{};
    int p = 0;
    for (int a = 0; a < F_FIELDS; ++a)
        for (int b = a + 1; b < F_FIELDS; ++b) { t.iu[p] = (unsigned char)a; t.ju[p] = (unsigned char)b; ++p; }
    for (; p < PAD_PAIRS; ++p) { t.iu[p] = 0; t.ju[p] = 0; }
    return t;
}
__constant__ PairTab PT = make_pairs();

__device__ __forceinline__ unsigned short bf16u(float v) {
    unsigned u = __float_as_uint(v);
    unsigned r = (u + 0x7fffu + ((u >> 16) & 1u)) >> 16;
    return (unsigned short)r;
}
__device__ __forceinline__ unsigned pk_bf16(float lo, float hi) {
    return (unsigned)bf16u(lo) | ((unsigned)bf16u(hi) << 16);
}
__device__ __forceinline__ float bflo(unsigned d) { return __uint_as_float(d << 16); }
__device__ __forceinline__ float bfhi(unsigned d) { return __uint_as_float(d & 0xffff0000u); }
__device__ __forceinline__ unsigned pk_trunc(float u, float cu) {
    return __builtin_amdgcn_perm(__float_as_uint(cu), __float_as_uint(u), 0x07060302u);
}
// non-temporal 16B load: global_load_dwordx4 with nt (L1 bypass)
__device__ __forceinline__ bf16x8 ntload16(const unsigned short* p) {
    i32x4 v = __builtin_nontemporal_load((const i32x4*)p);
    return __builtin_bit_cast(bf16x8, v);
}

// ---------------- K0: weight repack into lane-contiguous frag layouts ----------
__global__ __launch_bounds__(256) void k_wprep(const float* __restrict__ w1,
        const float* __restrict__ blw, unsigned short* __restrict__ w1catL,
        unsigned short* __restrict__ wcatL) {
    const int p = blockIdx.x;
    const int tid = threadIdx.x;
    if (p >= P_PAIRS) {
        int4 z = make_int4(0, 0, 0, 0);
        *(int4*)(w1catL + (size_t)p * 2048 + tid * 8) = z;
        if (tid < 64) *(int4*)(wcatL + (size_t)p * 512 + tid * 8) = z;
        return;
    }
    __shared__ float wu[1024], wv[1024], wb[256];
    ((float4*)wu)[tid] = ((const float4*)(w1 + (size_t)p * 1024))[tid];
    ((float4*)wv)[tid] = ((const float4*)(w1 + 332800 + (size_t)p * 1024))[tid];
    if (tid < 64) ((float4*)wb)[tid] = ((const float4*)(blw + (size_t)p * 256))[tid];
    __syncthreads();
    {   // w1catL[p][nt][lane][8]: element [o=nt*16+ln][k'=q*8+j], k'=2d+su
        int nt = tid >> 6, lane = tid & 63, ln = lane & 15, q = lane >> 4;
        int o = nt * 16 + ln;
        unsigned short outv[8];
        #pragma unroll
        for (int j = 0; j < 8; ++j) {
            int k = q * 8 + j, d = k >> 1, su = k & 1;
            outv[j] = bf16u(su ? wv[d * 64 + o] : wu[d * 64 + o]);
        }
        *(int4*)(w1catL + (size_t)p * 2048 + tid * 8) = *(const int4*)outv;
    }
    if (tid < 64) {  // wcatL[p][lane][8]: element [dout=ln][din=q*8+j], pad din>=16
        int ln = tid & 15, q = tid >> 4;
        unsigned short outv[8];
        #pragma unroll
        for (int j = 0; j < 8; ++j) {
            int din = q * 8 + j;
            outv[j] = (din < 16) ? bf16u(wb[din * 16 + ln]) : (unsigned short)0;
        }
        *(int4*)(wcatL + (size_t)p * 512 + tid * 8) = *(const int4*)outv;
    }
}

// LDS union: phase A (gather + pair loop) vs phase B (reduce + MLP tail)
union __align__(16) SMem {
    struct {
        unsigned short eS[ROWS * 424];   // 54272 B
        float aS[F_FIELDS * ROWS];       //  6656 B
    } a;                                 // 60928 B
    struct {
        unsigned ysh[8 * 8 * 64 * 4];    // 65536 B  [w][s][lane][4]
        float h1s[ROWS * 65];            // 16640 B  (pad 65 breaks conflicts)
        float h2s[ROWS * 36];            //  9216 B
    } b;                                 // 91392 B
};

// ---------------- K1: fully fused gather+SE+bilinear+GEMM+MLP ----------------
// grid 256 blocks x 512 thr (8 waves). Block owns 64 batch rows (4 m-tiles);
// wave w owns pairs [42w, 42w+42); epilogue reduces the 8 chunk-partials in
// LDS and runs BN1/ReLU -> w2 -> BN2/ReLU -> w3 -> sigmoid in-block.
__global__ __launch_bounds__(512, 2) void k_main(const int* __restrict__ x,
        const float* __restrict__ emb, const float* __restrict__ sw1,
        const float* __restrict__ sw2, const unsigned short* __restrict__ w1catL,
        const unsigned short* __restrict__ wcatL,
        const float* __restrict__ b1, const float* __restrict__ g1,
        const float* __restrict__ be1, const float* __restrict__ m1,
        const float* __restrict__ v1,
        const float* __restrict__ w2, const float* __restrict__ b2,
        const float* __restrict__ g2, const float* __restrict__ be2,
        const float* __restrict__ m2, const float* __restrict__ v2,
        const float* __restrict__ w3, const float* __restrict__ b3,
        float* __restrict__ out) {
    __shared__ SMem sm;
    __shared__ float z_s[ROWS][F_FIELDS];
    __shared__ float sw1_s[F_FIELDS * 13];
    __shared__ float sw2_s[13 * F_FIELDS];
    const int tid = threadIdx.x;
    const int b0 = blockIdx.x * ROWS;
    unsigned short* eS = sm.a.eS;
    float* aS = sm.a.aS;

    for (int i = tid; i < F_FIELDS * 13; i += 512) { sw1_s[i] = sw1[i]; sw2_s[i] = sw2[i]; }
    for (int idx = tid; idx < ROWS * F_FIELDS; idx += 512) {
        int r = idx / F_FIELDS, f = idx - r * F_FIELDS;
        int id = x[(b0 + r) * F_FIELDS + f] + f * 1000;
        const float4* src = (const float4*)(emb + (size_t)id * 16);
        float4 v0 = src[0], v1l = src[1], v2l = src[2], v3l = src[3];
        int4 o0, o1;
        o0.x = (int)pk_bf16(v0.x, v0.y);  o0.y = (int)pk_bf16(v0.z, v0.w);
        o0.z = (int)pk_bf16(v1l.x, v1l.y); o0.w = (int)pk_bf16(v1l.z, v1l.w);
        o1.x = (int)pk_bf16(v2l.x, v2l.y); o1.y = (int)pk_bf16(v2l.z, v2l.w);
        o1.z = (int)pk_bf16(v3l.x, v3l.y); o1.w = (int)pk_bf16(v3l.z, v3l.w);
        *(int4*)(eS + r * 424 + f * 16) = o0;
        *(int4*)(eS + r * 424 + f * 16 + 8) = o1;
        float s = v0.x + v0.y + v0.z + v0.w + v1l.x + v1l.y + v1l.z + v1l.w
                + v2l.x + v2l.y + v2l.z + v2l.w + v3l.x + v3l.y + v3l.z + v3l.w;
        z_s[r][f] = s * (1.0f / 16.0f);
    }
    __syncthreads();
    if (tid < ROWS) {
        float s1[13];
        #pragma unroll
        for (int o = 0; o < 13; ++o) {
            float acc0 = 0.f;
            #pragma unroll
            for (int f = 0; f < F_FIELDS; ++f) acc0 = fmaf(z_s[tid][f], sw1_s[f * 13 + o], acc0);
            s1[o] = fmaxf(acc0, 0.0f);
        }
        #pragma unroll
        for (int f = 0; f < F_FIELDS; ++f) {
            float acc0 = 0.f;
            #pragma unroll
            for (int o = 0; o < 13; ++o) acc0 = fmaf(s1[o], sw2_s[o * F_FIELDS + f], acc0);
            aS[f * ROWS + tid] = fmaxf(acc0, 0.0f);
        }
    }
    __syncthreads();

    // wave id is uniform; readfirstlane keeps pair bookkeeping scalar
    const int w    = __builtin_amdgcn_readfirstlane(tid >> 6);
    const int lane = tid & 63;
    const int ln   = lane & 15;
    const int q    = lane >> 4;
    const int p0 = w * 42, p1 = p0 + 42;

    f32x4 acc[4][4];
    #pragma unroll
    for (int a = 0; a < 4; ++a)
        #pragma unroll
        for (int b = 0; b < 4; ++b) acc[a][b] = (f32x4){0.f, 0.f, 0.f, 0.f};
    const f32x4 zero4 = {0.f, 0.f, 0.f, 0.f};

    // pair bookkeeping: (iu_c, ju_c) = indices of CURRENT pair p. Advance is
    // pure arithmetic (no SMEM in the loop). Pad pairs (p>=325) wrap to valid
    // (i,j) with zero weights -> contribute exactly 0, all reads in-bounds.
    int iu_c = PT.iu[p0];
    int ju_c = PT.ju[p0];
    bf16x8 eiB[4];
    float ai[4];
    #pragma unroll
    for (int mt = 0; mt < 4; ++mt) {
        eiB[mt] = __builtin_bit_cast(bf16x8,
            *(const int4*)(eS + (mt * 16 + ln) * 424 + iu_c * 16 + (q & 1) * 8));
        ai[mt] = aS[iu_c * ROWS + mt * 16 + ln];
    }
    bf16x8 wa_c = ntload16(wcatL + (size_t)p0 * 512 + lane * 8);
    bf16x8 wb_c[4];
    #pragma unroll
    for (int nt = 0; nt < 4; ++nt)
        wb_c[nt] = ntload16(w1catL + (size_t)p0 * 2048 + nt * 512 + lane * 8);
    f32x4 tc[4];
    #pragma unroll
    for (int mt = 0; mt < 4; ++mt)
        tc[mt] = __builtin_amdgcn_mfma_f32_16x16x32_bf16(wa_c, eiB[mt], zero4, 0, 0, 0);

    #pragma unroll 2
    for (int p = p0; p < p1; ++p) {
        const int pn = (p + 1 < p1) ? (p + 1) : p;
        bf16x8 wa_n = ntload16(wcatL + (size_t)pn * 512 + lane * 8);
        bf16x8 wb_n[4];
        #pragma unroll
        for (int nt = 0; nt < 4; ++nt)
            wb_n[nt] = ntload16(w1catL + (size_t)pn * 2048 + nt * 512 + lane * 8);

        // current pair's e_j/a_j (register-only addresses)
        const int ju = ju_c;
        uint2 ejv[4];
        float cv[4];
        #pragma unroll
        for (int mt = 0; mt < 4; ++mt) {
            ejv[mt] = *(const uint2*)(eS + (mt * 16 + ln) * 424 + ju * 16 + q * 4);
            cv[mt]  = ai[mt] * aS[ju * ROWS + mt * 16 + ln];
        }

        // advance (iu_c,ju_c) -> pair p+1 (arithmetic; wraps keep indices valid)
        const int iu_prev = iu_c;
        ++ju_c;
        if (ju_c == F_FIELDS) {
            ++iu_c;
            if (iu_c >= F_FIELDS - 1) iu_c = 0;
            ju_c = iu_c + 1;
        }
        if (iu_c != iu_prev) {
            #pragma unroll
            for (int mt = 0; mt < 4; ++mt) {
                eiB[mt] = __builtin_bit_cast(bf16x8,
                    *(const int4*)(eS + (mt * 16 + ln) * 424 + iu_c * 16 + (q & 1) * 8));
                ai[mt] = aS[iu_c * ROWS + mt * 16 + ln];
            }
        }

        __builtin_amdgcn_s_setprio(1);
        #pragma unroll
        for (int mt = 0; mt < 4; ++mt) {
            f32x4 t = tc[mt];
            float e0 = bflo(ejv[mt].x), e1 = bfhi(ejv[mt].x);
            float e2 = bflo(ejv[mt].y), e3 = bfhi(ejv[mt].y);
            float c  = cv[mt];
            float u0 = t[0] * e0, u1 = t[1] * e1, u2 = t[2] * e2, u3 = t[3] * e3;
            int4 af;
            af.x = (int)pk_trunc(u0, c * u0);
            af.y = (int)pk_trunc(u1, c * u1);
            af.z = (int)pk_trunc(u2, c * u2);
            af.w = (int)pk_trunc(u3, c * u3);
            bf16x8 A = __builtin_bit_cast(bf16x8, af);
            #pragma unroll
            for (int nt = 0; nt < 4; ++nt)
                acc[mt][nt] = __builtin_amdgcn_mfma_f32_16x16x32_bf16(A, wb_c[nt], acc[mt][nt], 0, 0, 0);
        }
        // t for pair p+1 computed LAST: wa_n has a full iteration of latency cover
        #pragma unroll
        for (int mt = 0; mt < 4; ++mt)
            tc[mt] = __builtin_amdgcn_mfma_f32_16x16x32_bf16(wa_n, eiB[mt], zero4, 0, 0, 0);
        __builtin_amdgcn_s_setprio(0);
        wa_c = wa_n;
        #pragma unroll
        for (int nt = 0; nt < 4; ++nt) wb_c[nt] = wb_n[nt];
    }

    // ---------------- fused epilogue ----------------
    __syncthreads();             // all eS/aS reads done; safe to reuse LDS
    unsigned* ysh = sm.b.ysh;
    float* h1s = sm.b.h1s;
    float* h2s = sm.b.h2s;
    #pragma unroll
    for (int mt = 0; mt < 4; ++mt)
        #pragma unroll
        for (int nh = 0; nh < 2; ++nh) {
            int nt0 = nh * 2, nt1 = nh * 2 + 1;
            int4 v;
            v.x = (int)pk_bf16(acc[mt][nt0][0], acc[mt][nt0][1]);
            v.y = (int)pk_bf16(acc[mt][nt0][2], acc[mt][nt0][3]);
            v.z = (int)pk_bf16(acc[mt][nt1][0], acc[mt][nt1][1]);
            v.w = (int)pk_bf16(acc[mt][nt1][2], acc[mt][nt1][3]);
            *(int4*)(ysh + ((w * 8 + mt * 2 + nh) * 64 + lane) * 4) = v;
        }
    __syncthreads();

    {   // 8-chunk reduce + BN1/ReLU: all 512 threads, subtile s = tid>>6
        const int s = tid >> 6, lane2 = tid & 63, ln2 = lane2 & 15, q2 = lane2 >> 4;
        const int mt = s >> 1, nh = s & 1;
        const int c0 = nh * 32 + ln2, c1 = c0 + 16;
        const float sc0 = g1[c0] * rsqrtf(v1[c0] + BN_EPS);
        const float of0 = be1[c0] + sc0 * (b1[c0] - m1[c0]);
        const float sc1 = g1[c1] * rsqrtf(v1[c1] + BN_EPS);
        const float of1 = be1[c1] + sc1 * (b1[c1] - m1[c1]);
        float s8[8];
        #pragma unroll
        for (int i = 0; i < 8; ++i) s8[i] = 0.f;
        #pragma unroll
        for (int wv = 0; wv < 8; ++wv) {
            int4 v = *(const int4*)(ysh + ((wv * 8 + s) * 64 + lane2) * 4);
            s8[0] += bflo((unsigned)v.x); s8[1] += bfhi((unsigned)v.x);
            s8[2] += bflo((unsigned)v.y); s8[3] += bfhi((unsigned)v.y);
            s8[4] += bflo((unsigned)v.z); s8[5] += bfhi((unsigned)v.z);
            s8[6] += bflo((unsigned)v.w); s8[7] += bfhi((unsigned)v.w);
        }
        const int row0 = mt * 16 + q2 * 4;
        #pragma unroll
        for (int r = 0; r < 4; ++r) {
            h1s[(row0 + r) * 65 + c0] = fmaxf(s8[r] * sc0 + of0, 0.f);
            h1s[(row0 + r) * 65 + c1] = fmaxf(s8[4 + r] * sc1 + of1, 0.f);
        }
    }
    __syncthreads();

    {   // w2 GEMM: row = tid>>3 (0..63), 4 outputs per thread
        const int row = tid >> 3, gg = tid & 7;
        const int o0 = gg * 4;
        float a0 = 0.f, a1 = 0.f, a2 = 0.f, a3 = 0.f;
        #pragma unroll 8
        for (int k = 0; k < 64; ++k) {
            float hk = h1s[row * 65 + k];
            float4 wv = *(const float4*)(w2 + k * 32 + o0);
            a0 = fmaf(hk, wv.x, a0);
            a1 = fmaf(hk, wv.y, a1);
            a2 = fmaf(hk, wv.z, a2);
            a3 = fmaf(hk, wv.w, a3);
        }
        const float4 g2v  = *(const float4*)(g2 + o0);
        const float4 b2v  = *(const float4*)(b2 + o0);
        const float4 m2v  = *(const float4*)(m2 + o0);
        const float4 v2v  = *(const float4*)(v2 + o0);
        const float4 be2v = *(const float4*)(be2 + o0);
        float4 hv;
        hv.x = fmaxf(g2v.x * (a0 + b2v.x - m2v.x) * rsqrtf(v2v.x + BN_EPS) + be2v.x, 0.f);
        hv.y = fmaxf(g2v.y * (a1 + b2v.y - m2v.y) * rsqrtf(v2v.y + BN_EPS) + be2v.y, 0.f);
        hv.z = fmaxf(g2v.z * (a2 + b2v.z - m2v.z) * rsqrtf(v2v.z + BN_EPS) + be2v.z, 0.f);
        hv.w = fmaxf(g2v.w * (a3 + b2v.w - m2v.w) * rsqrtf(v2v.w + BN_EPS) + be2v.w, 0.f);
        *(float4*)(h2s + row * 36 + o0) = hv;
    }
    __syncthreads();
    if (tid < ROWS) {
        float sacc = b3[0];
        #pragma unroll
        for (int k = 0; k < 32; ++k) sacc = fmaf(h2s[tid * 36 + k], w3[k], sacc);
        out[b0 + tid] = 1.0f / (1.0f + expf(-sacc));
    }
}

extern "C" void kernel_launch(void* const* d_in, const int* in_sizes, int n_in,
                              void* d_out, int out_size, void* d_ws, size_t ws_size,
                              hipStream_t stream) {
    const int*   x   = (const int*)d_in[0];
    const float* emb = (const float*)d_in[1];
    const float* sw1 = (const float*)d_in[2];
    const float* sw2 = (const float*)d_in[3];
    const float* blw = (const float*)d_in[4];
    const float* w1  = (const float*)d_in[5];
    const float* b1  = (const float*)d_in[6];
    const float* g1  = (const float*)d_in[7];
    const float* be1 = (const float*)d_in[8];
    const float* m1  = (const float*)d_in[9];
    const float* v1  = (const float*)d_in[10];
    const float* w2  = (const float*)d_in[11];
    const float* b2  = (const float*)d_in[12];
    const float* g2  = (const float*)d_in[13];
    const float* be2 = (const float*)d_in[14];
    const float* m2  = (const float*)d_in[15];
    const float* v2  = (const float*)d_in[16];
    const float* w3  = (const float*)d_in[17];
    const float* b3  = (const float*)d_in[18];
    float* out = (float*)d_out;

    // ws (bytes): w1catL 1,376,256 | wcatL 344,064 -> 1.72 MB
    char* ws = (char*)d_ws;
    unsigned short* w1catL = (unsigned short*)ws;
    unsigned short* wcatL  = (unsigned short*)(ws + 1376256);

    hipLaunchKernelGGL(k_wprep, dim3(PAD_PAIRS), dim3(256), 0, stream, w1, blw, w1catL, wcatL);
    hipLaunchKernelGGL(k_main,  dim3(BATCH / ROWS), dim3(512), 0, stream,
                       x, emb, sw1, sw2, w1catL, wcatL,
                       b1, g1, be1, m1, v1, w2, b2, g2, be2, m2, v2, w3, b3, out);
}

// Round 15
// 132.588 us; speedup vs baseline: 1.0752x; 1.0752x over previous
//
#include <hip/hip_runtime.h>
#include <cstdint>
#include <cstddef>

// FiBiNET fused inference — single fused MFMA kernel + weight repack.
// R22: dual-stream pair loop. Ledger: TLP (R16/R12), vmcnt (R14), prefetch
// (R13), bytes (R17/R19), MFMA-issue (R19), VALU-issue (R20), L1-share
// (R18), L1-bypass (R21b: -19%, L1 was helping) ALL refuted; best = R15
// (43.4us). No pipe >45%, slot time invariant to wave count => within-wave
// dependency-latency equilibrium. Unprobed axis: the pair loop is ONE
// serial chain (tc->glue->acc->tc). Split each wave's 42 pairs into two
// independent streams A=[42w,42w+21), B=[42w+21,42w+42), each with private
// (iu,ju,ei,ai,wa,wb,tc), bodies interleaved per iteration -> 2x
// schedulable ILP at every stall. Shared acc (pipelined accumulation, std
// K-loop pattern). Work totals/LDS/occupancy unchanged. Accum order changes
// (A/B interleave) — R18 already showed checker tolerates reorder (absmax
// 0.0). ~165 arch + 64 acc ~= 229 <= 256 budget. Base = R15 otherwise.

#define F_FIELDS 26
#define P_PAIRS 325
#define PAD_PAIRS 336
#define BATCH 16384
#define BN_EPS 1e-3f
#define ROWS 64   // batch rows per block = 4 m-tiles per wave
#define PPH 21    // pairs per stream (2 streams x 21 = 42 per wave)

typedef short bf16x8 __attribute__((ext_vector_type(8)));
typedef float f32x4 __attribute__((ext_vector_type(4)));

struct PairTab { unsigned char iu[PAD_PAIRS]; unsigned char ju[PAD_PAIRS]; };
static constexpr PairTab make_pairs() {
    PairTab t{};
    int p = 0;
    for (int a = 0; a < F_FIELDS; ++a)
        for (int b = a + 1; b < F_FIELDS; ++b) { t.iu[p] = (unsigned char)a; t.ju[p] = (unsigned char)b; ++p; }
    for (; p < PAD_PAIRS; ++p) { t.iu[p] = 0; t.ju[p] = 0; }
    return t;
}
__constant__ PairTab PT = make_pairs();

__device__ __forceinline__ unsigned short bf16u(float v) {
    unsigned u = __float_as_uint(v);
    unsigned r = (u + 0x7fffu + ((u >> 16) & 1u)) >> 16;
    return (unsigned short)r;
}
__device__ __forceinline__ unsigned pk_bf16(float lo, float hi) {
    return (unsigned)bf16u(lo) | ((unsigned)bf16u(hi) << 16);
}
__device__ __forceinline__ float bflo(unsigned d) { return __uint_as_float(d << 16); }
__device__ __forceinline__ float bfhi(unsigned d) { return __uint_as_float(d & 0xffff0000u); }
__device__ __forceinline__ unsigned pk_trunc(float u, float cu) {
    return __builtin_amdgcn_perm(__float_as_uint(cu), __float_as_uint(u), 0x07060302u);
}

// ---------------- K0: weight repack into lane-contiguous frag layouts ----------
__global__ __launch_bounds__(256) void k_wprep(const float* __restrict__ w1,
        const float* __restrict__ blw, unsigned short* __restrict__ w1catL,
        unsigned short* __restrict__ wcatL) {
    const int p = blockIdx.x;
    const int tid = threadIdx.x;
    if (p >= P_PAIRS) {
        int4 z = make_int4(0, 0, 0, 0);
        *(int4*)(w1catL + (size_t)p * 2048 + tid * 8) = z;
        if (tid < 64) *(int4*)(wcatL + (size_t)p * 512 + tid * 8) = z;
        return;
    }
    __shared__ float wu[1024], wv[1024], wb[256];
    ((float4*)wu)[tid] = ((const float4*)(w1 + (size_t)p * 1024))[tid];
    ((float4*)wv)[tid] = ((const float4*)(w1 + 332800 + (size_t)p * 1024))[tid];
    if (tid < 64) ((float4*)wb)[tid] = ((const float4*)(blw + (size_t)p * 256))[tid];
    __syncthreads();
    {   // w1catL[p][nt][lane][8]: element [o=nt*16+ln][k'=q*8+j], k'=2d+su
        int nt = tid >> 6, lane = tid & 63, ln = lane & 15, q = lane >> 4;
        int o = nt * 16 + ln;
        unsigned short outv[8];
        #pragma unroll
        for (int j = 0; j < 8; ++j) {
            int k = q * 8 + j, d = k >> 1, su = k & 1;
            outv[j] = bf16u(su ? wv[d * 64 + o] : wu[d * 64 + o]);
        }
        *(int4*)(w1catL + (size_t)p * 2048 + tid * 8) = *(const int4*)outv;
    }
    if (tid < 64) {  // wcatL[p][lane][8]: element [dout=ln][din=q*8+j], pad din>=16
        int ln = tid & 15, q = tid >> 4;
        unsigned short outv[8];
        #pragma unroll
        for (int j = 0; j < 8; ++j) {
            int din = q * 8 + j;
            outv[j] = (din < 16) ? bf16u(wb[din * 16 + ln]) : (unsigned short)0;
        }
        *(int4*)(wcatL + (size_t)p * 512 + tid * 8) = *(const int4*)outv;
    }
}

// LDS union: phase A (gather + pair loop) vs phase B (reduce + MLP tail)
union __align__(16) SMem {
    struct {
        unsigned short eS[ROWS * 424];   // 54272 B
        float aS[F_FIELDS * ROWS];       //  6656 B
    } a;                                 // 60928 B
    struct {
        unsigned ysh[8 * 8 * 64 * 4];    // 65536 B  [w][s][lane][4]
        float h1s[ROWS * 65];            // 16640 B  (pad 65 breaks conflicts)
        float h2s[ROWS * 36];            //  9216 B
    } b;                                 // 91392 B
};

// one stream step: consume pair (iu_/ju_ state), prefetch pn, glue+MFMA.
// All state arrays are stream-private; acc/eS/aS/lane vars from scope.
#define STREAM_STEP(iu_, ju_, ei_, ai_, wa_, wb_, tc_, pn_) do {                        \
    bf16x8 wa_n = __builtin_bit_cast(bf16x8, *(const int4*)(wcatL + (size_t)(pn_) * 512 + lane * 8)); \
    bf16x8 wb_n0 = __builtin_bit_cast(bf16x8, *(const int4*)(w1catL + (size_t)(pn_) * 2048 + 0 * 512 + lane * 8)); \
    bf16x8 wb_n1 = __builtin_bit_cast(bf16x8, *(const int4*)(w1catL + (size_t)(pn_) * 2048 + 1 * 512 + lane * 8)); \
    bf16x8 wb_n2 = __builtin_bit_cast(bf16x8, *(const int4*)(w1catL + (size_t)(pn_) * 2048 + 2 * 512 + lane * 8)); \
    bf16x8 wb_n3 = __builtin_bit_cast(bf16x8, *(const int4*)(w1catL + (size_t)(pn_) * 2048 + 3 * 512 + lane * 8)); \
    const int ju = ju_;                                                                 \
    uint2 ejv[4]; float cv[4];                                                          \
    _Pragma("unroll") for (int mt = 0; mt < 4; ++mt) {                                  \
        ejv[mt] = *(const uint2*)(eS + (mt * 16 + ln) * 424 + ju * 16 + q * 4);         \
        cv[mt]  = ai_[mt] * aS[ju * ROWS + mt * 16 + ln];                               \
    }                                                                                   \
    const int iu_prev = iu_;                                                            \
    ++ju_;                                                                              \
    if (ju_ == F_FIELDS) {                                                              \
        ++iu_;                                                                          \
        if (iu_ >= F_FIELDS - 1) iu_ = 0;                                               \
        ju_ = iu_ + 1;                                                                  \
    }                                                                                   \
    if (iu_ != iu_prev) {                                                               \
        _Pragma("unroll") for (int mt = 0; mt < 4; ++mt) {                              \
            ei_[mt] = __builtin_bit_cast(bf16x8,                                        \
                *(const int4*)(eS + (mt * 16 + ln) * 424 + iu_ * 16 + (q & 1) * 8));    \
            ai_[mt] = aS[iu_ * ROWS + mt * 16 + ln];                                    \
        }                                                                               \
    }                                                                                   \
    __builtin_amdgcn_s_setprio(1);                                                      \
    _Pragma("unroll") for (int mt = 0; mt < 4; ++mt) {                                  \
        f32x4 t = tc_[mt];                                                              \
        float e0 = bflo(ejv[mt].x), e1 = bfhi(ejv[mt].x);                               \
        float e2 = bflo(ejv[mt].y), e3 = bfhi(ejv[mt].y);                               \
        float c  = cv[mt];                                                              \
        float u0 = t[0] * e0, u1 = t[1] * e1, u2 = t[2] * e2, u3 = t[3] * e3;           \
        int4 af;                                                                        \
        af.x = (int)pk_trunc(u0, c * u0);                                               \
        af.y = (int)pk_trunc(u1, c * u1);                                               \
        af.z = (int)pk_trunc(u2, c * u2);                                               \
        af.w = (int)pk_trunc(u3, c * u3);                                               \
        bf16x8 A_ = __builtin_bit_cast(bf16x8, af);                                     \
        acc[mt][0] = __builtin_amdgcn_mfma_f32_16x16x32_bf16(A_, wb_[0], acc[mt][0], 0, 0, 0); \
        acc[mt][1] = __builtin_amdgcn_mfma_f32_16x16x32_bf16(A_, wb_[1], acc[mt][1], 0, 0, 0); \
        acc[mt][2] = __builtin_amdgcn_mfma_f32_16x16x32_bf16(A_, wb_[2], acc[mt][2], 0, 0, 0); \
        acc[mt][3] = __builtin_amdgcn_mfma_f32_16x16x32_bf16(A_, wb_[3], acc[mt][3], 0, 0, 0); \
    }                                                                                   \
    _Pragma("unroll") for (int mt = 0; mt < 4; ++mt)                                    \
        tc_[mt] = __builtin_amdgcn_mfma_f32_16x16x32_bf16(wa_n, ei_[mt], zero4, 0, 0, 0); \
    __builtin_amdgcn_s_setprio(0);                                                      \
    wa_ = wa_n;                                                                         \
    wb_[0] = wb_n0; wb_[1] = wb_n1; wb_[2] = wb_n2; wb_[3] = wb_n3;                     \
} while (0)

// ---------------- K1: fully fused gather+SE+bilinear+GEMM+MLP ----------------
// grid 256 blocks x 512 thr (8 waves). Block owns 64 batch rows (4 m-tiles);
// wave w owns pairs [42w, 42w+42) as two independent 21-pair streams;
// epilogue reduces the 8 chunk-partials in LDS and runs BN1/ReLU -> w2 ->
// BN2/ReLU -> w3 -> sigmoid in-block.
__global__ __launch_bounds__(512, 2) void k_main(const int* __restrict__ x,
        const float* __restrict__ emb, const float* __restrict__ sw1,
        const float* __restrict__ sw2, const unsigned short* __restrict__ w1catL,
        const unsigned short* __restrict__ wcatL,
        const float* __restrict__ b1, const float* __restrict__ g1,
        const float* __restrict__ be1, const float* __restrict__ m1,
        const float* __restrict__ v1,
        const float* __restrict__ w2, const float* __restrict__ b2,
        const float* __restrict__ g2, const float* __restrict__ be2,
        const float* __restrict__ m2, const float* __restrict__ v2,
        const float* __restrict__ w3, const float* __restrict__ b3,
        float* __restrict__ out) {
    __shared__ SMem sm;
    __shared__ float z_s[ROWS][F_FIELDS];
    __shared__ float sw1_s[F_FIELDS * 13];
    __shared__ float sw2_s[13 * F_FIELDS];
    const int tid = threadIdx.x;
    const int b0 = blockIdx.x * ROWS;
    unsigned short* eS = sm.a.eS;
    float* aS = sm.a.aS;

    for (int i = tid; i < F_FIELDS * 13; i += 512) { sw1_s[i] = sw1[i]; sw2_s[i] = sw2[i]; }
    for (int idx = tid; idx < ROWS * F_FIELDS; idx += 512) {
        int r = idx / F_FIELDS, f = idx - r * F_FIELDS;
        int id = x[(b0 + r) * F_FIELDS + f] + f * 1000;
        const float4* src = (const float4*)(emb + (size_t)id * 16);
        float4 v0 = src[0], v1l = src[1], v2l = src[2], v3l = src[3];
        int4 o0, o1;
        o0.x = (int)pk_bf16(v0.x, v0.y);  o0.y = (int)pk_bf16(v0.z, v0.w);
        o0.z = (int)pk_bf16(v1l.x, v1l.y); o0.w = (int)pk_bf16(v1l.z, v1l.w);
        o1.x = (int)pk_bf16(v2l.x, v2l.y); o1.y = (int)pk_bf16(v2l.z, v2l.w);
        o1.z = (int)pk_bf16(v3l.x, v3l.y); o1.w = (int)pk_bf16(v3l.z, v3l.w);
        *(int4*)(eS + r * 424 + f * 16) = o0;
        *(int4*)(eS + r * 424 + f * 16 + 8) = o1;
        float s = v0.x + v0.y + v0.z + v0.w + v1l.x + v1l.y + v1l.z + v1l.w
                + v2l.x + v2l.y + v2l.z + v2l.w + v3l.x + v3l.y + v3l.z + v3l.w;
        z_s[r][f] = s * (1.0f / 16.0f);
    }
    __syncthreads();
    if (tid < ROWS) {
        float s1[13];
        #pragma unroll
        for (int o = 0; o < 13; ++o) {
            float acc0 = 0.f;
            #pragma unroll
            for (int f = 0; f < F_FIELDS; ++f) acc0 = fmaf(z_s[tid][f], sw1_s[f * 13 + o], acc0);
            s1[o] = fmaxf(acc0, 0.0f);
        }
        #pragma unroll
        for (int f = 0; f < F_FIELDS; ++f) {
            float acc0 = 0.f;
            #pragma unroll
            for (int o = 0; o < 13; ++o) acc0 = fmaf(s1[o], sw2_s[o * F_FIELDS + f], acc0);
            aS[f * ROWS + tid] = fmaxf(acc0, 0.0f);
        }
    }
    __syncthreads();

    // wave id is uniform; readfirstlane keeps pair bookkeeping scalar
    const int w    = __builtin_amdgcn_readfirstlane(tid >> 6);
    const int lane = tid & 63;
    const int ln   = lane & 15;
    const int q    = lane >> 4;
    const int p0A = w * 42;          // stream A: [p0A, p0A+21)
    const int p0B = w * 42 + PPH;    // stream B: [p0B, p0B+21)

    f32x4 acc[4][4];
    #pragma unroll
    for (int a = 0; a < 4; ++a)
        #pragma unroll
        for (int b = 0; b < 4; ++b) acc[a][b] = (f32x4){0.f, 0.f, 0.f, 0.f};
    const f32x4 zero4 = {0.f, 0.f, 0.f, 0.f};

    // ---- stream A state ----
    int iuA = PT.iu[p0A], juA = PT.ju[p0A];
    bf16x8 eA[4]; float aiA[4];
    #pragma unroll
    for (int mt = 0; mt < 4; ++mt) {
        eA[mt] = __builtin_bit_cast(bf16x8,
            *(const int4*)(eS + (mt * 16 + ln) * 424 + iuA * 16 + (q & 1) * 8));
        aiA[mt] = aS[iuA * ROWS + mt * 16 + ln];
    }
    bf16x8 waA = __builtin_bit_cast(bf16x8, *(const int4*)(wcatL + (size_t)p0A * 512 + lane * 8));
    bf16x8 wbA[4];
    #pragma unroll
    for (int nt = 0; nt < 4; ++nt)
        wbA[nt] = __builtin_bit_cast(bf16x8, *(const int4*)(w1catL + (size_t)p0A * 2048 + nt * 512 + lane * 8));
    f32x4 tcA[4];
    #pragma unroll
    for (int mt = 0; mt < 4; ++mt)
        tcA[mt] = __builtin_amdgcn_mfma_f32_16x16x32_bf16(waA, eA[mt], zero4, 0, 0, 0);

    // ---- stream B state ----
    int iuB = PT.iu[p0B], juB = PT.ju[p0B];
    bf16x8 eB[4]; float aiB[4];
    #pragma unroll
    for (int mt = 0; mt < 4; ++mt) {
        eB[mt] = __builtin_bit_cast(bf16x8,
            *(const int4*)(eS + (mt * 16 + ln) * 424 + iuB * 16 + (q & 1) * 8));
        aiB[mt] = aS[iuB * ROWS + mt * 16 + ln];
    }
    bf16x8 waB = __builtin_bit_cast(bf16x8, *(const int4*)(wcatL + (size_t)p0B * 512 + lane * 8));
    bf16x8 wbB[4];
    #pragma unroll
    for (int nt = 0; nt < 4; ++nt)
        wbB[nt] = __builtin_bit_cast(bf16x8, *(const int4*)(w1catL + (size_t)p0B * 2048 + nt * 512 + lane * 8));
    f32x4 tcB[4];
    #pragma unroll
    for (int mt = 0; mt < 4; ++mt)
        tcB[mt] = __builtin_amdgcn_mfma_f32_16x16x32_bf16(waB, eB[mt], zero4, 0, 0, 0);

    #pragma unroll 1
    for (int i = 0; i < PPH; ++i) {
        const int pnA = (i + 1 < PPH) ? (p0A + i + 1) : (p0A + PPH - 1);
        const int pnB = (i + 1 < PPH) ? (p0B + i + 1) : (p0B + PPH - 1);
        STREAM_STEP(iuA, juA, eA, aiA, waA, wbA, tcA, pnA);
        STREAM_STEP(iuB, juB, eB, aiB, waB, wbB, tcB, pnB);
    }

    // ---------------- fused epilogue ----------------
    __syncthreads();             // all eS/aS reads done; safe to reuse LDS
    unsigned* ysh = sm.b.ysh;
    float* h1s = sm.b.h1s;
    float* h2s = sm.b.h2s;
    #pragma unroll
    for (int mt = 0; mt < 4; ++mt)
        #pragma unroll
        for (int nh = 0; nh < 2; ++nh) {
            int nt0 = nh * 2, nt1 = nh * 2 + 1;
            int4 v;
            v.x = (int)pk_bf16(acc[mt][nt0][0], acc[mt][nt0][1]);
            v.y = (int)pk_bf16(acc[mt][nt0][2], acc[mt][nt0][3]);
            v.z = (int)pk_bf16(acc[mt][nt1][0], acc[mt][nt1][1]);
            v.w = (int)pk_bf16(acc[mt][nt1][2], acc[mt][nt1][3]);
            *(int4*)(ysh + ((w * 8 + mt * 2 + nh) * 64 + lane) * 4) = v;
        }
    __syncthreads();

    {   // 8-chunk reduce + BN1/ReLU: all 512 threads, subtile s = tid>>6
        const int s = tid >> 6, lane2 = tid & 63, ln2 = lane2 & 15, q2 = lane2 >> 4;
        const int mt = s >> 1, nh = s & 1;
        const int c0 = nh * 32 + ln2, c1 = c0 + 16;
        const float sc0 = g1[c0] * rsqrtf(v1[c0] + BN_EPS);
        const float of0 = be1[c0] + sc0 * (b1[c0] - m1[c0]);
        const float sc1 = g1[c1] * rsqrtf(v1[c1] + BN_EPS);
        const float of1 = be1[c1] + sc1 * (b1[c1] - m1[c1]);
        float s8[8];
        #pragma unroll
        for (int i = 0; i < 8; ++i) s8[i] = 0.f;
        #pragma unroll
        for (int wv = 0; wv < 8; ++wv) {
            int4 v = *(const int4*)(ysh + ((wv * 8 + s) * 64 + lane2) * 4);
            s8[0] += bflo((unsigned)v.x); s8[1] += bfhi((unsigned)v.x);
            s8[2] += bflo((unsigned)v.y); s8[3] += bfhi((unsigned)v.y);
            s8[4] += bflo((unsigned)v.z); s8[5] += bfhi((unsigned)v.z);
            s8[6] += bflo((unsigned)v.w); s8[7] += bfhi((unsigned)v.w);
        }
        const int row0 = mt * 16 + q2 * 4;
        #pragma unroll
        for (int r = 0; r < 4; ++r) {
            h1s[(row0 + r) * 65 + c0] = fmaxf(s8[r] * sc0 + of0, 0.f);
            h1s[(row0 + r) * 65 + c1] = fmaxf(s8[4 + r] * sc1 + of1, 0.f);
        }
    }
    __syncthreads();

    {   // w2 GEMM: row = tid>>3 (0..63), 4 outputs per thread
        const int row = tid >> 3, gg = tid & 7;
        const int o0 = gg * 4;
        float a0 = 0.f, a1 = 0.f, a2 = 0.f, a3 = 0.f;
        #pragma unroll 8
        for (int k = 0; k < 64; ++k) {
            float hk = h1s[row * 65 + k];
            float4 wv = *(const float4*)(w2 + k * 32 + o0);
            a0 = fmaf(hk, wv.x, a0);
            a1 = fmaf(hk, wv.y, a1);
            a2 = fmaf(hk, wv.z, a2);
            a3 = fmaf(hk, wv.w, a3);
        }
        const float4 g2v  = *(const float4*)(g2 + o0);
        const float4 b2v  = *(const float4*)(b2 + o0);
        const float4 m2v  = *(const float4*)(m2 + o0);
        const float4 v2v  = *(const float4*)(v2 + o0);
        const float4 be2v = *(const float4*)(be2 + o0);
        float4 hv;
        hv.x = fmaxf(g2v.x * (a0 + b2v.x - m2v.x) * rsqrtf(v2v.x + BN_EPS) + be2v.x, 0.f);
        hv.y = fmaxf(g2v.y * (a1 + b2v.y - m2v.y) * rsqrtf(v2v.y + BN_EPS) + be2v.y, 0.f);
        hv.z = fmaxf(g2v.z * (a2 + b2v.z - m2v.z) * rsqrtf(v2v.z + BN_EPS) + be2v.z, 0.f);
        hv.w = fmaxf(g2v.w * (a3 + b2v.w - m2v.w) * rsqrtf(v2v.w + BN_EPS) + be2v.w, 0.f);
        *(float4*)(h2s + row * 36 + o0) = hv;
    }
    __syncthreads();
    if (tid < ROWS) {
        float sacc = b3[0];
        #pragma unroll
        for (int k = 0; k < 32; ++k) sacc = fmaf(h2s[tid * 36 + k], w3[k], sacc);
        out[b0 + tid] = 1.0f / (1.0f + expf(-sacc));
    }
}

extern "C" void kernel_launch(void* const* d_in, const int* in_sizes, int n_in,
                              void* d_out, int out_size, void* d_ws, size_t ws_size,
                              hipStream_t stream) {
    const int*   x   = (const int*)d_in[0];
    const float* emb = (const float*)d_in[1];
    const float* sw1 = (const float*)d_in[2];
    const float* sw2 = (const float*)d_in[3];
    const float* blw = (const float*)d_in[4];
    const float* w1  = (const float*)d_in[5];
    const float* b1  = (const float*)d_in[6];
    const float* g1  = (const float*)d_in[7];
    const float* be1 = (const float*)d_in[8];
    const float* m1  = (const float*)d_in[9];
    const float* v1  = (const float*)d_in[10];
    const float* w2  = (const float*)d_in[11];
    const float* b2  = (const float*)d_in[12];
    const float* g2  = (const float*)d_in[13];
    const float* be2 = (const float*)d_in[14];
    const float* m2  = (const float*)d_in[15];
    const float* v2  = (const float*)d_in[16];
    const float* w3  = (const float*)d_in[17];
    const float* b3  = (const float*)d_in[18];
    float* out = (float*)d_out;

    // ws (bytes): w1catL 1,376,256 | wcatL 344,064 -> 1.72 MB
    char* ws = (char*)d_ws;
    unsigned short* w1catL = (unsigned short*)ws;
    unsigned short* wcatL  = (unsigned short*)(ws + 1376256);

    hipLaunchKernelGGL(k_wprep, dim3(PAD_PAIRS), dim3(256), 0, stream, w1, blw, w1catL, wcatL);
    hipLaunchKernelGGL(k_main,  dim3(BATCH / ROWS), dim3(512), 0, stream,
                       x, emb, sw1, sw2, w1catL, wcatL,
                       b1, g1, be1, m1, v1, w2, b2, g2, be2, m2, v2, w3, b3, out);
}